// Round 1
// baseline (23.986 us; speedup 1.0000x reference)
//
#include <hip/hip_runtime.h>
#include <math.h>

// Problem constants
#define N_CL 128      // N clusters
#define M_SPK 16      // M rows per cluster
#define P_DIM 256     // feature dim
#define NM 2048       // N*M rows
static constexpr float EPS_NORM = 1e-12f;
static constexpr float EPS_LOG  = 1e-9f;
static constexpr float W_ABS    = 10.0f;   // abs(W)
static constexpr float B_OFF    = -5.0f;   // B

// ws layout (float offsets):
//   centT      [P_DIM][N_CL]  @ 0        (32768 floats) cent_sum transposed, p-major
//   csn        [N_CL]         @ 32768    ||cent_sum[n]||^2
//   scale_oth  [N_CL]         @ 32896    1/sqrt(csn + M^2*eps)
//   enorm2     [NM]           @ 33024    ||e_k||^2
//   re         [NM]           @ 35072    1/sqrt(enorm2 + eps)
//   rowloss    [NM]           @ 37120    per-row loss term
#define WS_CENTT   0
#define WS_CSN     32768
#define WS_SCALE   32896
#define WS_ENORM2  33024
#define WS_RE      35072
#define WS_ROWLOSS 37120

__device__ __forceinline__ float waveReduceSum(float x) {
    #pragma unroll
    for (int off = 32; off > 0; off >>= 1)
        x += __shfl_xor(x, off, 64);
    return x;
}

// Kernel 1: per-cluster centroid sums (transposed), cluster norms, per-row e norms.
// grid = 128 (one block per cluster n), block = 256 (one thread per p)
__global__ __launch_bounds__(256)
void k1_stats(const float* __restrict__ e, float* __restrict__ ws) {
    const int n    = blockIdx.x;
    const int p    = threadIdx.x;
    const int wid  = p >> 6;
    const int lane = p & 63;

    float* centT     = ws + WS_CENTT;
    float* csn       = ws + WS_CSN;
    float* scale_oth = ws + WS_SCALE;
    float* enorm2    = ws + WS_ENORM2;
    float* re        = ws + WS_RE;

    __shared__ float part[M_SPK][4];
    __shared__ float cpart[4];

    float acc = 0.f;
    #pragma unroll
    for (int m = 0; m < M_SPK; ++m) {
        float v = e[(n * M_SPK + m) * P_DIM + p];
        acc += v;
        float sq = waveReduceSum(v * v);
        if (lane == 0) part[m][wid] = sq;
    }
    // transposed store so k2's reads across n' are coalesced
    centT[p * N_CL + n] = acc;

    float c2 = waveReduceSum(acc * acc);
    if (lane == 0) cpart[wid] = c2;
    __syncthreads();

    if (p < M_SPK) {
        int row = n * M_SPK + p;
        float s2 = part[p][0] + part[p][1] + part[p][2] + part[p][3];
        enorm2[row] = s2;
        re[row] = 1.0f / sqrtf(s2 + EPS_NORM);
    }
    if (p == 0) {
        float t = cpart[0] + cpart[1] + cpart[2] + cpart[3];
        csn[n] = t;
        // (1/M) / sqrt(||cent/M||^2 + eps) == 1/sqrt(||cent||^2 + M^2*eps)
        scale_oth[n] = 1.0f / sqrtf(t + (float)(M_SPK * M_SPK) * EPS_NORM);
    }
}

// Kernel 2: s[k][n'] + per-row logsumexp loss term.
// grid = 2048 (one block per row k), block = 128 (one thread per cluster n')
__global__ __launch_bounds__(128)
void k2_main(const float* __restrict__ e, const float* __restrict__ ws,
             float* __restrict__ d_out, float* __restrict__ rowloss) {
    const int k = blockIdx.x;
    const int t = threadIdx.x;   // n'

    const float* centT     = ws + WS_CENTT;
    const float* csn       = ws + WS_CSN;
    const float* scale_oth = ws + WS_SCALE;
    const float* enorm2    = ws + WS_ENORM2;
    const float* re        = ws + WS_RE;

    __shared__ float eL[P_DIM];
    __shared__ float wpart[2];
    __shared__ float sOwn;

    eL[t]       = e[k * P_DIM + t];
    eL[t + 128] = e[k * P_DIM + 128 + t];
    __syncthreads();

    float dot = 0.f;
    #pragma unroll 16
    for (int p = 0; p < P_DIM; ++p)
        dot = fmaf(eL[p], centT[p * N_CL + t], dot);  // coalesced across t

    const int nk = k >> 4;           // k / M
    const float rek = re[k];
    float s;
    if (t == nk) {
        const float e2  = enorm2[k];
        const float num = (dot - e2) * (1.0f / (M_SPK - 1));
        const float h2  = (csn[nk] - 2.0f * dot + e2)
                          * (1.0f / ((M_SPK - 1) * (M_SPK - 1)));
        s = W_ABS * (num * rek / sqrtf(h2 + EPS_NORM)) + B_OFF;
        sOwn = s;
    } else {
        s = W_ABS * (dot * rek * scale_oth[t]) + B_OFF;
    }
    d_out[1 + k * N_CL + t] = s;

    // row logsumexp (matches ref: log(sum(exp(s)) + eps)) — no max-shift needed (s <= 5)
    float ex = expf(s);
    float wsum = waveReduceSum(ex);
    const int lane = t & 63;
    const int wid  = t >> 6;
    if (lane == 0) wpart[wid] = wsum;
    __syncthreads();
    if (t == 0) {
        float tot = wpart[0] + wpart[1];
        rowloss[k] = logf(tot + EPS_LOG) - sOwn;
    }
}

// Kernel 3: mean of rowloss -> d_out[0]
__global__ __launch_bounds__(256)
void k3_reduce(const float* __restrict__ rowloss, float* __restrict__ d_out) {
    __shared__ float wpart[4];
    const int t = threadIdx.x;
    float sum = 0.f;
    #pragma unroll
    for (int i = 0; i < NM / 256; ++i)
        sum += rowloss[i * 256 + t];
    sum = waveReduceSum(sum);
    if ((t & 63) == 0) wpart[t >> 6] = sum;
    __syncthreads();
    if (t == 0)
        d_out[0] = (wpart[0] + wpart[1] + wpart[2] + wpart[3]) * (1.0f / NM);
}

extern "C" void kernel_launch(void* const* d_in, const int* in_sizes, int n_in,
                              void* d_out, int out_size, void* d_ws, size_t ws_size,
                              hipStream_t stream) {
    const float* e = (const float*)d_in[0];
    float* out = (float*)d_out;
    float* ws  = (float*)d_ws;

    k1_stats<<<N_CL, 256, 0, stream>>>(e, ws);
    k2_main<<<NM, 128, 0, stream>>>(e, ws, out, ws + WS_ROWLOSS);
    k3_reduce<<<1, 256, 0, stream>>>(ws + WS_ROWLOSS, out);
}